// Round 5
// baseline (413.623 us; speedup 1.0000x reference)
//
#include <hip/hip_runtime.h>

#define HW 3136
#define NB 8
#define CD 128
#define NT (HW/64)
// C^-0.5 * log2(e), folded into the Q projection so attn can use exp2 directly
#define QSCALE 0.12751750206f

typedef __attribute__((ext_vector_type(8))) short short8;
typedef __attribute__((ext_vector_type(4))) short short4v;
typedef __attribute__((ext_vector_type(4))) float floatx4;
typedef __attribute__((ext_vector_type(4))) unsigned short ushort4v;

static __device__ __forceinline__ unsigned short f2b(float f){
  union { float f; unsigned u; } v; v.f = f;
  unsigned r = v.u + 0x7FFFu + ((v.u >> 16) & 1u);
  return (unsigned short)(r >> 16);
}
static __device__ __forceinline__ float b2f(unsigned short h){
  union { unsigned u; float f; } v; v.u = ((unsigned)h) << 16;
  return v.f;
}

// K=16 bf16 MFMA: builtin spelling differs across ROCm versions; hedge.
#if __has_builtin(__builtin_amdgcn_mfma_f32_16x16x16bf16_1k)
#define MFMA16(a,b,c) __builtin_amdgcn_mfma_f32_16x16x16bf16_1k(a,b,c,0,0,0)
#elif __has_builtin(__builtin_amdgcn_mfma_f32_16x16x16_bf16)
#define MFMA16(a,b,c) __builtin_amdgcn_mfma_f32_16x16x16_bf16(a,b,c,0,0,0)
#else
static __device__ __forceinline__ floatx4 mfma16_asm(short4v a, short4v b, floatx4 c){
  floatx4 d;
  asm volatile("v_mfma_f32_16x16x16_bf16 %0, %1, %2, %3\n\ts_nop 7\n\ts_nop 7"
               : "=v"(d) : "v"(a), "v"(b), "v"(c));
  return d;
}
#define MFMA16(a,b,c) mfma16_asm(a,b,c)
#endif

// ---------------------------------------------------------------------------
// 1x1 conv projections via MFMA (unchanged — control kernel)
// ---------------------------------------------------------------------------
__global__ __launch_bounds__(256) void proj_kernel(
    const float* __restrict__ s, const float* __restrict__ t1, const float* __restrict__ t2,
    const float* __restrict__ wq, const float* __restrict__ bq,
    const float* __restrict__ wk, const float* __restrict__ bk,
    const float* __restrict__ wv, const float* __restrict__ bv,
    unsigned short* __restrict__ qkv)
{
  __shared__ __align__(16) unsigned short WL[CD][136];
  __shared__ __align__(16) unsigned short xsT[64][136];
  const int job = blockIdx.z;
  const float* x; const float* w; const float* bias; float scl; int cmajor; size_t dstoff;
  switch(job){
    case 0: x=s;  w=wq; bias=bq; scl=QSCALE; cmajor=0; dstoff=0; break;
    case 1: x=t1; w=wk; bias=bk; scl=1.f;    cmajor=0; dstoff=1; break;
    case 2: x=t1; w=wv; bias=bv; scl=1.f;    cmajor=1; dstoff=2; break;
    case 3: x=t2; w=wk; bias=bk; scl=1.f;    cmajor=0; dstoff=3; break;
    default:x=t2; w=wv; bias=bv; scl=1.f;    cmajor=1; dstoff=4; break;
  }
  const size_t TS = (size_t)NB*HW*CD;
  const int b   = blockIdx.y;
  const int hw0 = blockIdx.x * 64;
  const int tid = threadIdx.x;

  for (int i = 0; i < 16; i++){
    int flat = tid + i*256;
    int o = flat >> 5, cq = (flat & 31)*4;
    floatx4 wv4 = *(const floatx4*)(w + (size_t)o*CD + cq);
    ushort4v pk;
    for (int j=0;j<4;j++) pk[j] = f2b(wv4[j]);
    *(ushort4v*)&WL[o][cq] = pk;
  }
  const float* xb = x + (size_t)b*CD*HW + hw0;
  for (int i = 0; i < 8; i++){
    int flat = (tid + i*256)*4;
    int c = flat >> 6, hh = flat & 63;
    floatx4 xv = *(const floatx4*)(xb + (size_t)c*HW + hh);
    for (int j=0;j<4;j++) xsT[hh+j][c] = f2b(xv[j]);
  }
  __syncthreads();

  const int m = tid & 15, quad = (tid >> 4) & 3, wv_ = tid >> 6;
  short8 af[4];
  for (int dk=0;dk<4;dk++)
    af[dk] = *(const short8*)&xsT[wv_*16 + m][dk*32 + quad*8];
  float bb[8];
  for (int nt=0;nt<8;nt++) bb[nt] = bias[nt*16 + m];

  unsigned short* dstK = qkv + dstoff*TS + ((size_t)b*HW + hw0)*CD;
  unsigned short* dstV = qkv + dstoff*TS + (size_t)b*CD*HW;
  for (int nt=0;nt<8;nt++){
    floatx4 acc = {bb[nt],bb[nt],bb[nt],bb[nt]};
    for (int dk=0;dk<4;dk++){
      short8 bf = *(const short8*)&WL[nt*16 + m][dk*32 + quad*8];
      acc = __builtin_amdgcn_mfma_f32_16x16x32_bf16(af[dk], bf, acc, 0,0,0);
    }
    if (!cmajor){
      for (int r=0;r<4;r++)
        dstK[(size_t)(wv_*16 + quad*4 + r)*CD + nt*16 + m] = f2b(acc[r]*scl);
    } else {
      ushort4v pk;
      for (int r=0;r<4;r++) pk[r] = f2b(acc[r]*scl);
      *(ushort4v*)&dstV[(size_t)(nt*16 + m)*HW + hw0 + wv_*16 + quad*4] = pk;
    }
  }
}

// ---------------------------------------------------------------------------
// Flash attention, barrier-free direct-L2 edition.
// R4 post-mortem: pipes effectively SERIALIZED — MFMA demand (123K cyc/CU) =
// measured MfmaUtil 32%, exp2 demand (77K) = VALUBusy 25%, sum+LDS ~= measured
// 2530 cyc/block-tile. Barriers lock both resident waves into the same phase,
// so MFMA/VALU/LDS never overlap. But in the k-split design each wave reads
// ONLY its own 16-k slice of K and V — the shared-LDS double-buffer and every
// main-loop barrier were pure coordination overhead. And staging doesn't save
// L2 traffic (DMA reads L2 too; no cross-wave sharing of slices).
// Fix: fragments load DIRECTLY from L2 (XCD-pinned, ~3.2MB/XCD working set):
//  - af: 16B/lane, 64B-per-row coalesced; vf: 8B/lane, 4 waves share lines.
//  - NO LDS in main loop, NO DMA, NO swizzle, ZERO barriers: waves free-run,
//    one wave's exp2 overlaps another's MFMA; L2 latency absorbed by drift.
// L2 volume: 32KB/block-tile (each byte once per block) ~= 46us floor.
// Regs: qf 64 + af 16 + vf 16 + misc ~= 125 VGPR + 128 AGPR Oc -> 2 waves/SIMD.
// ---------------------------------------------------------------------------
__global__ __launch_bounds__(256,2) void attn_kernel(
    const unsigned short* __restrict__ qkv,
    unsigned short* __restrict__ Og)
{
  __shared__ __align__(16) float smem[4*2304 + 256 + 64]; // 38144 B, epilogue only
  float* lrb  = smem + 4*2304;   // [4 wv][64 q]
  float* invL = lrb + 256;       // [64 q]

  const int l  = blockIdx.x;     // 392 = 8 XCD-pinned b values x 49 qt
  const int b  = l & 7;
  const int qt = l >> 3;
  const size_t TS = (size_t)NB*HW*CD;
  const unsigned short* Q = qkv + (size_t)b*HW*CD;

  const int tid  = threadIdx.x;
  const int wv_  = tid >> 6;
  const int lane = tid & 63;
  const int m    = lane & 15;
  const int quad = lane >> 4;
  const int q0   = qt*64;

  // Q B-fragments, iter- and teacher-invariant
  short8 qf[4][4];
#pragma unroll
  for (int qs=0;qs<4;qs++){
    const unsigned short* qr = Q + (size_t)(q0 + qs*16 + m)*CD + quad*8;
#pragma unroll
    for (int dk=0;dk<4;dk++) qf[qs][dk] = *(const short8*)(qr + dk*32);
  }

  for (int t2=0; t2<2; t2++){
    const unsigned short* K = qkv + TS*(size_t)(1 + 2*t2) + (size_t)b*HW*CD;
    const unsigned short* V = qkv + TS*(size_t)(2 + 2*t2) + (size_t)b*CD*HW;
    // per-lane fragment base addresses (advance by k-tile each iter)
    const unsigned short* ka = K + (size_t)(wv_*16 + m)*CD + quad*8;
    const unsigned short* va = V + (size_t)m*HW + wv_*16 + quad*4;

    floatx4 Oc[8][4];                // k-partial O^T: [ct][qs] (AGPRs)
#pragma unroll
    for (int i=0;i<8;i++)
#pragma unroll
      for (int j=0;j<4;j++) Oc[i][j] = (floatx4)0.f;
    float lr[4] = {0.f,0.f,0.f,0.f};

    for (int kt = 0; kt < NT; kt++){
      // K fragment: own-wave 16 rows, 16B/lane (rows 64B-coalesced per dk)
      short8 af[4];
#pragma unroll
      for (int dk=0;dk<4;dk++)
        af[dk] = *(const short8*)(ka + dk*32);
      // V fragment: own-wave 16-k window, 8B/lane; independent of QK ->
      // compiler issues early, waits only before PV
      short4v vf[8];
#pragma unroll
      for (int ct=0;ct<8;ct++)
        vf[ct] = *(const short4v*)(va + (size_t)ct*16*HW);
      ka += 64*CD; va += 64;

      // QK: S^T[wv's 16k][64q]; lane holds k = wv*16+quad*4+r, q = q0+m
      short4v pfv[4];
#pragma unroll
      for (int qs=0;qs<4;qs++){
        floatx4 acc = (floatx4)0.f;
#pragma unroll
        for (int dk=0;dk<4;dk++)
          acc = __builtin_amdgcn_mfma_f32_16x16x32_bf16(af[dk], qf[qs][dk], acc, 0,0,0);
        union { float f; unsigned u; } c0, c1, c2, c3;
        c0.f = __builtin_amdgcn_exp2f(acc[0]);
        c1.f = __builtin_amdgcn_exp2f(acc[1]);
        c2.f = __builtin_amdgcn_exp2f(acc[2]);
        c3.f = __builtin_amdgcn_exp2f(acc[3]);
        lr[qs] += (c0.f + c1.f) + (c2.f + c3.f);
        union { unsigned u[2]; short4v s; } pk;
        pk.u[0] = (c1.u & 0xFFFF0000u) | (c0.u >> 16);   // truncate-pack
        pk.u[1] = (c3.u & 0xFFFF0000u) | (c2.u >> 16);
        pfv[qs] = pk.s;
      }

      // PV (K=16): O^T += V^T[c][wv's 16k] * P^T  (S^T D-frag == B-frag identity)
#pragma unroll
      for (int ct=0;ct<8;ct++){
#pragma unroll
        for (int qs=0;qs<4;qs++)
          Oc[ct][qs] = MFMA16(vf[ct], pfv[qs], Oc[ct][qs]);
      }
    }

    // ---- epilogue: cross-wave reduction of lr and O partials ----
#pragma unroll
    for (int qs=0;qs<4;qs++){
      lr[qs] += __shfl_xor(lr[qs], 16, 64);
      lr[qs] += __shfl_xor(lr[qs], 32, 64);
    }
    if (quad == 0){
#pragma unroll
      for (int qs=0;qs<4;qs++) lrb[wv_*64 + qs*16 + m] = lr[qs];
    }
    __syncthreads();
    if (tid < 64)
      invL[tid] = 1.f/(lrb[tid] + lrb[64+tid] + lrb[128+tid] + lrb[192+tid]);
    __syncthreads();

    float* Of = smem;
    unsigned short* ob = Og + ((size_t)t2*NB + b)*HW*CD + (size_t)q0*CD;
    const int qlr = wv_*16 + (lane>>2);
    const int c8  = (lane&3)*8;
#pragma unroll
    for (int rd=0; rd<4; rd++){
#pragma unroll
      for (int cc=0; cc<2; cc++){
#pragma unroll
        for (int qs=0; qs<4; qs++)
          *(floatx4*)&Of[wv_*2304 + (qs*16+m)*36 + cc*16 + quad*4] = Oc[rd*2+cc][qs];
      }
      __syncthreads();
      floatx4 s0 = (floatx4)0.f, s1 = (floatx4)0.f;
#pragma unroll
      for (int w=0; w<4; w++){
        s0 += *(const floatx4*)&Of[w*2304 + qlr*36 + c8];
        s1 += *(const floatx4*)&Of[w*2304 + qlr*36 + c8 + 4];
      }
      float iv = invL[qlr];
      short8 o;
#pragma unroll
      for (int j=0;j<4;j++){
        o[j]   = (short)f2b(s0[j]*iv);
        o[4+j] = (short)f2b(s1[j]*iv);
      }
      *(short8*)&ob[(size_t)qlr*CD + rd*32 + c8] = o;
      __syncthreads();
    }
  }
}

// ---------------------------------------------------------------------------
// out[b,c,hw] = s[b,c,hw] + 0.5*(O1[b,hw,c] + O2[b,hw,c])  (unchanged)
// ---------------------------------------------------------------------------
__global__ __launch_bounds__(256) void combine_kernel(
    const float* __restrict__ s, const unsigned short* __restrict__ Og,
    float* __restrict__ out)
{
  __shared__ float T[32][129];
  const int b   = blockIdx.y;
  const int hw0 = blockIdx.x * 32;
  const int tid = threadIdx.x;
  const unsigned short* O1 = Og + ((size_t)b*HW + hw0)*CD;
  const unsigned short* O2 = O1 + (size_t)NB*HW*CD;
  for (int i=0;i<2;i++){
    int flat = (tid + i*256)*8;
    int row = flat >> 7, col = flat & 127;
    short8 a  = *(const short8*)(O1 + (size_t)row*CD + col);
    short8 c2 = *(const short8*)(O2 + (size_t)row*CD + col);
    for (int j=0;j<8;j++)
      T[row][col+j] = 0.5f*(b2f((unsigned short)a[j]) + b2f((unsigned short)c2[j]));
  }
  __syncthreads();
  const int c  = tid >> 1;
  const int h0 = (tid & 1)*16;
  const float* sr = s   + ((size_t)b*CD + c)*HW + hw0 + h0;
  float*     orow = out + ((size_t)b*CD + c)*HW + hw0 + h0;
  for (int j0=0;j0<16;j0+=4){
    floatx4 sv = *(const floatx4*)(sr + j0);
    floatx4 ov;
    for (int jj=0;jj<4;jj++) ov[jj] = sv[jj] + T[h0+j0+jj][c];
    *(floatx4*)(orow + j0) = ov;
  }
}

extern "C" void kernel_launch(void* const* d_in, const int* in_sizes, int n_in,
                              void* d_out, int out_size, void* d_ws, size_t ws_size,
                              hipStream_t stream)
{
  const float* s  = (const float*)d_in[0];
  const float* t1 = (const float*)d_in[1];
  const float* t2 = (const float*)d_in[2];
  const float* wq = (const float*)d_in[3];
  const float* bq = (const float*)d_in[4];
  const float* wk = (const float*)d_in[5];
  const float* bk = (const float*)d_in[6];
  const float* wv = (const float*)d_in[7];
  const float* bv = (const float*)d_in[8];
  float* out = (float*)d_out;

  unsigned short* qkv = (unsigned short*)d_ws;
  unsigned short* Og  = qkv + (size_t)5*NB*HW*CD;

  hipLaunchKernelGGL(proj_kernel,    dim3(49,8,5), dim3(256), 0, stream,
                     s,t1,t2,wq,bq,wk,bk,wv,bv,qkv);
  hipLaunchKernelGGL(attn_kernel,    dim3(392),    dim3(256), 0, stream, qkv, Og);
  hipLaunchKernelGGL(combine_kernel, dim3(98,8),   dim3(256), 0, stream, s, Og, out);
}

// Round 6
// 357.625 us; speedup vs baseline: 1.1566x; 1.1566x over previous
//
#include <hip/hip_runtime.h>

#define HW 3136
#define NB 8
#define CD 128
#define NT (HW/64)
// C^-0.5 * log2(e), folded into the Q projection so attn can use exp2 directly
#define QSCALE 0.12751750206f

typedef __attribute__((ext_vector_type(8))) short short8;
typedef __attribute__((ext_vector_type(4))) short short4v;
typedef __attribute__((ext_vector_type(4))) float floatx4;
typedef __attribute__((ext_vector_type(4))) unsigned short ushort4v;

static __device__ __forceinline__ unsigned short f2b(float f){
  union { float f; unsigned u; } v; v.f = f;
  unsigned r = v.u + 0x7FFFu + ((v.u >> 16) & 1u);
  return (unsigned short)(r >> 16);
}
static __device__ __forceinline__ float b2f(unsigned short h){
  union { unsigned u; float f; } v; v.u = ((unsigned)h) << 16;
  return v.f;
}

// K=16 bf16 MFMA: builtin spelling differs across ROCm versions; hedge.
#if __has_builtin(__builtin_amdgcn_mfma_f32_16x16x16bf16_1k)
#define MFMA16(a,b,c) __builtin_amdgcn_mfma_f32_16x16x16bf16_1k(a,b,c,0,0,0)
#elif __has_builtin(__builtin_amdgcn_mfma_f32_16x16x16_bf16)
#define MFMA16(a,b,c) __builtin_amdgcn_mfma_f32_16x16x16_bf16(a,b,c,0,0,0)
#else
static __device__ __forceinline__ floatx4 mfma16_asm(short4v a, short4v b, floatx4 c){
  floatx4 d;
  asm volatile("v_mfma_f32_16x16x16_bf16 %0, %1, %2, %3\n\ts_nop 7\n\ts_nop 7"
               : "=v"(d) : "v"(a), "v"(b), "v"(c));
  return d;
}
#define MFMA16(a,b,c) mfma16_asm(a,b,c)
#endif

// ---------------------------------------------------------------------------
// One-time W f32->bf16 conversion (3 blocks). Amortizes f2b + halves W traffic
// for the 1960 proj blocks that previously each re-staged f32 W.
// ---------------------------------------------------------------------------
__global__ __launch_bounds__(256) void wconv_kernel(
    const float* __restrict__ wq, const float* __restrict__ wk,
    const float* __restrict__ wv, unsigned short* __restrict__ Wb)
{
  const float* src = blockIdx.x==0 ? wq : (blockIdx.x==1 ? wk : wv);
  unsigned short* dst = Wb + (size_t)blockIdx.x*CD*CD;
  for (int i = threadIdx.x; i < CD*CD/4; i += 256){
    floatx4 v = *(const floatx4*)(src + (size_t)i*4);
    ushort4v p;
#pragma unroll
    for (int j=0;j<4;j++) p[j] = f2b(v[j]);
    *(ushort4v*)(dst + (size_t)i*4) = p;
  }
}

// ---------------------------------------------------------------------------
// 1x1 conv projections via MFMA: Y[b,hw,o] = sum_c X[b,c,hw] * W[o,c] + bias[o]
// W now read directly from L2 as bf16 fragments (32KB hot per XCD): no WL
// staging, LDS 53->17.4KB (occupancy up ~3x for latency hiding).
// ---------------------------------------------------------------------------
__global__ __launch_bounds__(256) void proj_kernel(
    const float* __restrict__ s, const float* __restrict__ t1, const float* __restrict__ t2,
    const float* __restrict__ bq, const float* __restrict__ bk, const float* __restrict__ bv,
    const unsigned short* __restrict__ Wb,
    unsigned short* __restrict__ qkv)
{
  __shared__ __align__(16) unsigned short xsT[64][136];  // X^T bf16 [hw_local][c]
  const int job = blockIdx.z;
  const float* x; const float* bias; float scl; int cmajor; size_t dstoff; int wsel;
  switch(job){
    case 0: x=s;  wsel=0; bias=bq; scl=QSCALE; cmajor=0; dstoff=0; break;
    case 1: x=t1; wsel=1; bias=bk; scl=1.f;    cmajor=0; dstoff=1; break;
    case 2: x=t1; wsel=2; bias=bv; scl=1.f;    cmajor=1; dstoff=2; break;
    case 3: x=t2; wsel=1; bias=bk; scl=1.f;    cmajor=0; dstoff=3; break;
    default:x=t2; wsel=2; bias=bv; scl=1.f;    cmajor=1; dstoff=4; break;
  }
  const size_t TS = (size_t)NB*HW*CD;
  const int b   = blockIdx.y;
  const int hw0 = blockIdx.x * 64;
  const int tid = threadIdx.x;
  const unsigned short* W = Wb + (size_t)wsel*CD*CD;

  // stage X^T (transpose during store; scalar b16 writes, one-time cost)
  const float* xb = x + (size_t)b*CD*HW + hw0;
  for (int i = 0; i < 8; i++){
    int flat = (tid + i*256)*4;             // c*64 + hh
    int c = flat >> 6, hh = flat & 63;
    floatx4 xv = *(const floatx4*)(xb + (size_t)c*HW + hh);
    for (int j=0;j<4;j++) xsT[hh+j][c] = f2b(xv[j]);
  }
  __syncthreads();

  const int m = tid & 15, quad = (tid >> 4) & 3, wv_ = tid >> 6;
  short8 af[4];
#pragma unroll
  for (int dk=0;dk<4;dk++)
    af[dk] = *(const short8*)&xsT[wv_*16 + m][dk*32 + quad*8];
  float bb[8];
#pragma unroll
  for (int nt=0;nt<8;nt++) bb[nt] = bias[nt*16 + m];

  unsigned short* dstK = qkv + dstoff*TS + ((size_t)b*HW + hw0)*CD;
  unsigned short* dstV = qkv + dstoff*TS + (size_t)b*CD*HW;
#pragma unroll
  for (int nt=0;nt<8;nt++){
    floatx4 acc = {bb[nt],bb[nt],bb[nt],bb[nt]};
#pragma unroll
    for (int dk=0;dk<4;dk++){
      short8 bf = *(const short8*)&W[(size_t)(nt*16 + m)*CD + dk*32 + quad*8];
      acc = __builtin_amdgcn_mfma_f32_16x16x32_bf16(af[dk], bf, acc, 0,0,0);
    }
    if (!cmajor){
      for (int r=0;r<4;r++)
        dstK[(size_t)(wv_*16 + quad*4 + r)*CD + nt*16 + m] = f2b(acc[r]*scl);
    } else {
      ushort4v pk;
      for (int r=0;r<4;r++) pk[r] = f2b(acc[r]*scl);
      *(ushort4v*)&dstV[(size_t)(nt*16 + m)*HW + hw0 + wv_*16 + quad*4] = pk;
    }
  }
}

// ---------------------------------------------------------------------------
// Flash attention — main loop byte-identical to R4 (best verified: 158us).
// R5 lesson: direct-L2 fragment loads are transaction-bound (MfmaUtil 17%,
// HBM 1.3%); LDS staging is the coalescing device, keep it.
// NEW: fused epilogue. This block computes BOTH teachers for the same
// (b, q-range) and Oc is already channel-major O^T[c][q]:
//   t2=0: write normalized O1 as f32 to Otmp[b][c][hw]
//   t2=1: out = s + 0.5*(O1 + O2)  -- same threads, same addresses, L2-hot.
// Eliminates combine_kernel and the bf16 O round-trip entirely.
// ---------------------------------------------------------------------------
__global__ __launch_bounds__(256,2) void attn_kernel(
    const unsigned short* __restrict__ qkv,
    const float* __restrict__ s,
    float* __restrict__ out,
    float* __restrict__ Otmp)
{
  // shorts: K0 [0,8192) V0 [8192,16384) K1 [16384,24576) V1 [24576,32768)
  __shared__ __align__(16) unsigned short smem[32768 + 512 + 128]; // 66816 B
  float* lrb  = (float*)(smem + 32768);        // [4 wv][64 q]
  float* invL = (float*)(smem + 32768 + 512);  // [64 q]

  const int l  = blockIdx.x;       // 392 = 8 XCD-pinned b values x 49 qt
  const int b  = l & 7;
  const int qt = l >> 3;
  const size_t TS = (size_t)NB*HW*CD;
  const unsigned short* Q = qkv + (size_t)b*HW*CD;

  const int tid  = threadIdx.x;
  const int wv_  = tid >> 6;
  const int lane = tid & 63;
  const int m    = lane & 15;
  const int quad = lane >> 4;
  const int q0   = qt*64;

  // DMA source offsets (shorts), pre-swizzled so linear LDS dest + swizzled
  // ds_read agree: LDS(row, col16) holds logical col16 ^ (row&7).
  unsigned koff[4];
  {
    const int kr_ = lane >> 4, kc_ = lane & 15;
#pragma unroll
    for (int i=0;i<4;i++){
      const int krow = wv_*16 + i*4 + kr_;
      koff[i] = (unsigned)(krow*CD + ((kc_ ^ ((i*4 + kr_) & 7))*8));
    }
  }
  const int      vrow0 = wv_*32 + (lane>>3);
  const unsigned vcs   = (unsigned)(((lane&7) ^ (lane>>3))*8);

  // Q B-fragments, iter- and teacher-invariant
  short8 qf[4][4];
#pragma unroll
  for (int qs=0;qs<4;qs++){
    const unsigned short* qr = Q + (size_t)(q0 + qs*16 + m)*CD + quad*8;
#pragma unroll
    for (int dk=0;dk<4;dk++) qf[qs][dk] = *(const short8*)(qr + dk*32);
  }

#define STAGE(buf, ktile) do { \
    const unsigned short* kt_src = K + (size_t)(ktile)*64*CD; \
    const unsigned short* vt_src = V + (size_t)(ktile)*64; \
    unsigned short* kl = (unsigned short*)smem + (buf)*16384 + wv_*2048; \
    unsigned short* vl = (unsigned short*)smem + (buf)*16384 + 8192 + wv_*2048; \
    _Pragma("unroll") \
    for (int i_=0;i_<4;i_++) \
      __builtin_amdgcn_global_load_lds( \
        (const __attribute__((address_space(1))) void*)(kt_src + koff[i_]), \
        (__attribute__((address_space(3))) void*)(kl + i_*512), 16, 0, 0); \
    _Pragma("unroll") \
    for (int i_=0;i_<4;i_++) \
      __builtin_amdgcn_global_load_lds( \
        (const __attribute__((address_space(1))) void*)(vt_src + (size_t)(vrow0 + i_*8)*HW + vcs), \
        (__attribute__((address_space(3))) void*)(vl + i_*512), 16, 0, 0); \
  } while(0)

  for (int t2=0; t2<2; t2++){
    const unsigned short* K = qkv + TS*(size_t)(1 + 2*t2) + (size_t)b*HW*CD;
    const unsigned short* V = qkv + TS*(size_t)(2 + 2*t2) + (size_t)b*CD*HW;

    floatx4 Oc[8][4];                  // k-partial O^T: [ct][qs] (AGPRs)
#pragma unroll
    for (int i=0;i<8;i++)
#pragma unroll
      for (int j=0;j<4;j++) Oc[i][j] = (floatx4)0.f;
    float lr[4] = {0.f,0.f,0.f,0.f};

    STAGE(0, 0);                       // prologue: tile 0 -> buf0

    for (int kt = 0; kt < NT; kt++){
      const int cur = kt & 1;
      __builtin_amdgcn_s_barrier();    // B1: all waves done computing buf[cur^1]
      if (kt < NT-1){
        STAGE(cur^1, kt+1);            // async DMA next tile
        asm volatile("s_waitcnt vmcnt(8)" ::: "memory");  // own buf[cur] DMAs done
      } else {
        asm volatile("s_waitcnt vmcnt(0)" ::: "memory");
      }
      __builtin_amdgcn_sched_barrier(0);
      __builtin_amdgcn_s_barrier();    // B2: everyone's buf[cur] complete
      asm volatile("" ::: "memory");

      const unsigned short* Kc = (const unsigned short*)smem + cur*16384;
      const unsigned short* Vc = (const unsigned short*)smem + cur*16384 + 8192;

      // QK: S^T[wv's 16k][64q]; A-frag = own-wave K rows, swizzled read
      short8 af[4];
#pragma unroll
      for (int dk=0;dk<4;dk++)
        af[dk] = *(const short8*)&Kc[(wv_*16 + m)*128 + (((dk*4 + quad) ^ (m & 7))*8)];

      short4v pfv[4];
#pragma unroll
      for (int qs=0;qs<4;qs++){
        floatx4 acc = (floatx4)0.f;
#pragma unroll
        for (int dk=0;dk<4;dk++)
          acc = __builtin_amdgcn_mfma_f32_16x16x32_bf16(af[dk], qf[qs][dk], acc, 0,0,0);
        union { float f; unsigned u; } c0, c1, c2, c3;
        c0.f = __builtin_amdgcn_exp2f(acc[0]);
        c1.f = __builtin_amdgcn_exp2f(acc[1]);
        c2.f = __builtin_amdgcn_exp2f(acc[2]);
        c3.f = __builtin_amdgcn_exp2f(acc[3]);
        lr[qs] += (c0.f + c1.f) + (c2.f + c3.f);
        union { unsigned u[2]; short4v s; } pk;
        pk.u[0] = (c1.u & 0xFFFF0000u) | (c0.u >> 16);
        pk.u[1] = (c3.u & 0xFFFF0000u) | (c2.u >> 16);
        pfv[qs] = pk.s;
      }

      // PV (K=16): O^T += V^T[c][wv's 16k] * P^T; swizzled b64 A-frag reads
#pragma unroll
      for (int ct=0;ct<8;ct++){
        short4v vf = *(const short4v*)&Vc[(ct*16 + m)*64 +
                       (((2*wv_ + (quad>>1)) ^ (m & 7))*8) + (quad&1)*4];
#pragma unroll
        for (int qs=0;qs<4;qs++)
          Oc[ct][qs] = MFMA16(vf, pfv[qs], Oc[ct][qs]);
      }
    }

    // ---- epilogue: cross-wave reduction of lr and O partials ----
#pragma unroll
    for (int qs=0;qs<4;qs++){
      lr[qs] += __shfl_xor(lr[qs], 16, 64);
      lr[qs] += __shfl_xor(lr[qs], 32, 64);
    }
    if (quad == 0){
#pragma unroll
      for (int qs=0;qs<4;qs++) lrb[wv_*64 + qs*16 + m] = lr[qs];
    }
    __syncthreads();
    if (tid < 64)
      invL[tid] = 1.f/(lrb[tid] + lrb[64+tid] + lrb[128+tid] + lrb[192+tid]);
    __syncthreads();

    float* Of = (float*)smem;          // overlaps K/V buffers (all reads done)
    float* OT = Otmp + (size_t)b*CD*HW;
    const float* sb = s + (size_t)b*CD*HW;
    float* ob = out + (size_t)b*CD*HW;
    const int qlr = wv_*16 + (lane>>2);
    const int c8  = (lane&3)*8;
#pragma unroll
    for (int rd=0; rd<4; rd++){
#pragma unroll
      for (int cc=0; cc<2; cc++){
#pragma unroll
        for (int qs=0; qs<4; qs++)
          *(floatx4*)&Of[wv_*2304 + (qs*16+m)*36 + cc*16 + quad*4] = Oc[rd*2+cc][qs];
      }
      __syncthreads();
      floatx4 s0 = (floatx4)0.f, s1 = (floatx4)0.f;
#pragma unroll
      for (int w=0; w<4; w++){
        s0 += *(const floatx4*)&Of[w*2304 + qlr*36 + c8];
        s1 += *(const floatx4*)&Of[w*2304 + qlr*36 + c8 + 4];
      }
      float iv = invL[qlr];
      if (t2 == 0){
#pragma unroll
        for (int j=0;j<4;j++){
          OT[(size_t)(rd*32 + c8 + j)*HW     + q0 + qlr] = s0[j]*iv;
          OT[(size_t)(rd*32 + c8 + 4 + j)*HW + q0 + qlr] = s1[j]*iv;
        }
      } else {
#pragma unroll
        for (int j=0;j<4;j++){
          size_t o0 = (size_t)(rd*32 + c8 + j)*HW     + q0 + qlr;
          size_t o1 = (size_t)(rd*32 + c8 + 4 + j)*HW + q0 + qlr;
          ob[o0] = sb[o0] + 0.5f*(OT[o0] + s0[j]*iv);
          ob[o1] = sb[o1] + 0.5f*(OT[o1] + s1[j]*iv);
        }
      }
      __syncthreads();
    }
  }
#undef STAGE
}

extern "C" void kernel_launch(void* const* d_in, const int* in_sizes, int n_in,
                              void* d_out, int out_size, void* d_ws, size_t ws_size,
                              hipStream_t stream)
{
  const float* s  = (const float*)d_in[0];
  const float* t1 = (const float*)d_in[1];
  const float* t2 = (const float*)d_in[2];
  const float* wq = (const float*)d_in[3];
  const float* bq = (const float*)d_in[4];
  const float* wk = (const float*)d_in[5];
  const float* bk = (const float*)d_in[6];
  const float* wv = (const float*)d_in[7];
  const float* bv = (const float*)d_in[8];
  float* out = (float*)d_out;

  unsigned short* qkv = (unsigned short*)d_ws;                 // 5*NB*HW*CD bf16
  float* Otmp = (float*)(qkv + (size_t)5*NB*HW*CD);            // NB*CD*HW f32
  unsigned short* Wb = (unsigned short*)(Otmp + (size_t)NB*CD*HW); // 3*CD*CD bf16

  hipLaunchKernelGGL(wconv_kernel, dim3(3),      dim3(256), 0, stream, wq, wk, wv, Wb);
  hipLaunchKernelGGL(proj_kernel,  dim3(49,8,5), dim3(256), 0, stream,
                     s, t1, t2, bq, bk, bv, Wb, qkv);
  hipLaunchKernelGGL(attn_kernel,  dim3(392),    dim3(256), 0, stream, qkv, s, out, Otmp);
}

// Round 7
// 314.625 us; speedup vs baseline: 1.3147x; 1.1367x over previous
//
#include <hip/hip_runtime.h>

#define HW 3136
#define NB 8
#define CD 128
#define NT (HW/64)
// C^-0.5 * log2(e), folded into the Q projection so attn can use exp2 directly
#define QSCALE 0.12751750206f

typedef __attribute__((ext_vector_type(8))) short short8;
typedef __attribute__((ext_vector_type(4))) short short4v;
typedef __attribute__((ext_vector_type(4))) float floatx4;
typedef __attribute__((ext_vector_type(4))) unsigned short ushort4v;

static __device__ __forceinline__ unsigned short f2b(float f){
  union { float f; unsigned u; } v; v.f = f;
  unsigned r = v.u + 0x7FFFu + ((v.u >> 16) & 1u);
  return (unsigned short)(r >> 16);
}
static __device__ __forceinline__ float b2f(unsigned short h){
  union { unsigned u; float f; } v; v.u = ((unsigned)h) << 16;
  return v.f;
}

// K=16 bf16 MFMA: builtin spelling differs across ROCm versions; hedge.
#if __has_builtin(__builtin_amdgcn_mfma_f32_16x16x16bf16_1k)
#define MFMA16(a,b,c) __builtin_amdgcn_mfma_f32_16x16x16bf16_1k(a,b,c,0,0,0)
#elif __has_builtin(__builtin_amdgcn_mfma_f32_16x16x16_bf16)
#define MFMA16(a,b,c) __builtin_amdgcn_mfma_f32_16x16x16_bf16(a,b,c,0,0,0)
#else
static __device__ __forceinline__ floatx4 mfma16_asm(short4v a, short4v b, floatx4 c){
  floatx4 d;
  asm volatile("v_mfma_f32_16x16x16_bf16 %0, %1, %2, %3\n\ts_nop 7\n\ts_nop 7"
               : "=v"(d) : "v"(a), "v"(b), "v"(c));
  return d;
}
#define MFMA16(a,b,c) mfma16_asm(a,b,c)
#endif

// ---------------------------------------------------------------------------
// One-time W f32->bf16 conversion (3 blocks).
// ---------------------------------------------------------------------------
__global__ __launch_bounds__(256) void wconv_kernel(
    const float* __restrict__ wq, const float* __restrict__ wk,
    const float* __restrict__ wv, unsigned short* __restrict__ Wb)
{
  const float* src = blockIdx.x==0 ? wq : (blockIdx.x==1 ? wk : wv);
  unsigned short* dst = Wb + (size_t)blockIdx.x*CD*CD;
  for (int i = threadIdx.x; i < CD*CD/4; i += 256){
    floatx4 v = *(const floatx4*)(src + (size_t)i*4);
    ushort4v p;
#pragma unroll
    for (int j=0;j<4;j++) p[j] = f2b(v[j]);
    *(ushort4v*)(dst + (size_t)i*4) = p;
  }
}

// ---------------------------------------------------------------------------
// 1x1 conv projections. R6 post-mortem: proj ~120us across ALL rounds (rest =
// total-attn: 127/127/129/132) — per-block X^T staging + block count dominate,
// not W traffic. Fix: merge each teacher's K and V jobs into ONE block:
// one X^T staging serves both matmuls (t1/t2 HBM reads halve; af reused),
// grid 1960 -> 1176 blocks. job0=Q(s); job1=K1+V1(t1); job2=K2+V2(t2).
// ---------------------------------------------------------------------------
static __device__ __forceinline__ void proj_one(
    const short8* af, const unsigned short* __restrict__ W,
    const float* __restrict__ bias, float scl, int cmajor,
    unsigned short* __restrict__ dst, int hw0, int m, int quad, int wv_)
{
#pragma unroll
  for (int nt=0;nt<8;nt++){
    float bb = bias[nt*16 + m];
    floatx4 acc = {bb,bb,bb,bb};
#pragma unroll
    for (int dk=0;dk<4;dk++){
      short8 bf = *(const short8*)&W[(size_t)(nt*16 + m)*CD + dk*32 + quad*8];
      acc = __builtin_amdgcn_mfma_f32_16x16x32_bf16(af[dk], bf, acc, 0,0,0);
    }
    if (!cmajor){
      unsigned short* dstK = dst + (size_t)hw0*CD;
      for (int r=0;r<4;r++)
        dstK[(size_t)(wv_*16 + quad*4 + r)*CD + nt*16 + m] = f2b(acc[r]*scl);
    } else {
      ushort4v pk;
      for (int r=0;r<4;r++) pk[r] = f2b(acc[r]*scl);
      *(ushort4v*)&dst[(size_t)(nt*16 + m)*HW + hw0 + wv_*16 + quad*4] = pk;
    }
  }
}

__global__ __launch_bounds__(256) void proj_kernel(
    const float* __restrict__ s, const float* __restrict__ t1, const float* __restrict__ t2,
    const float* __restrict__ bq, const float* __restrict__ bk, const float* __restrict__ bv,
    const unsigned short* __restrict__ Wb,
    unsigned short* __restrict__ qkv)
{
  __shared__ __align__(16) unsigned short xsT[64][136];  // X^T bf16 [hw_local][c]
  const int job = blockIdx.z;
  const float* x = job==0 ? s : (job==1 ? t1 : t2);
  const size_t TS = (size_t)NB*HW*CD;
  const int b   = blockIdx.y;
  const int hw0 = blockIdx.x * 64;
  const int tid = threadIdx.x;

  // stage X^T (transpose during store; scalar b16 writes, once per block)
  const float* xb = x + (size_t)b*CD*HW + hw0;
  for (int i = 0; i < 8; i++){
    int flat = (tid + i*256)*4;             // c*64 + hh
    int c = flat >> 6, hh = flat & 63;
    floatx4 xv = *(const floatx4*)(xb + (size_t)c*HW + hh);
    for (int j=0;j<4;j++) xsT[hh+j][c] = f2b(xv[j]);
  }
  __syncthreads();

  const int m = tid & 15, quad = (tid >> 4) & 3, wv_ = tid >> 6;
  short8 af[4];
#pragma unroll
  for (int dk=0;dk<4;dk++)
    af[dk] = *(const short8*)&xsT[wv_*16 + m][dk*32 + quad*8];

  if (job == 0){
    proj_one(af, Wb, bq, QSCALE, 0,
             qkv + (size_t)b*HW*CD, hw0, m, quad, wv_);
  } else {
    const size_t koff_ = (size_t)(2*job - 1)*TS;
    const size_t voff_ = (size_t)(2*job    )*TS;
    proj_one(af, Wb + (size_t)CD*CD,   bk, 1.f, 0,
             qkv + koff_ + (size_t)b*HW*CD, hw0, m, quad, wv_);
    proj_one(af, Wb + (size_t)2*CD*CD, bv, 1.f, 1,
             qkv + voff_ + (size_t)b*CD*HW, hw0, m, quad, wv_);
  }
}

// ---------------------------------------------------------------------------
// Flash attention — byte-exact R4 revert (best verified: 158us).
// R6 lesson: fused channel-major f32 epilogue caused write-allocate/partial-
// line amplification (WRITE 12.5->136MB) + OT L2 eviction between phases.
// ---------------------------------------------------------------------------
__global__ __launch_bounds__(256,2) void attn_kernel(
    const unsigned short* __restrict__ qkv,
    unsigned short* __restrict__ Og)
{
  // shorts: K0 [0,8192) V0 [8192,16384) K1 [16384,24576) V1 [24576,32768)
  __shared__ __align__(16) unsigned short smem[32768 + 512 + 128]; // 66816 B
  float* lrb  = (float*)(smem + 32768);        // [4 wv][64 q]
  float* invL = (float*)(smem + 32768 + 512);  // [64 q]

  const int l  = blockIdx.x;       // 392 = 8 XCD-pinned b values x 49 qt
  const int b  = l & 7;
  const int qt = l >> 3;
  const size_t TS = (size_t)NB*HW*CD;
  const unsigned short* Q = qkv + (size_t)b*HW*CD;

  const int tid  = threadIdx.x;
  const int wv_  = tid >> 6;
  const int lane = tid & 63;
  const int m    = lane & 15;
  const int quad = lane >> 4;
  const int q0   = qt*64;

  // DMA source offsets (shorts), pre-swizzled so linear LDS dest + swizzled
  // ds_read agree: LDS(row, col16) holds logical col16 ^ (row&7).
  unsigned koff[4];
  {
    const int kr_ = lane >> 4, kc_ = lane & 15;
#pragma unroll
    for (int i=0;i<4;i++){
      const int krow = wv_*16 + i*4 + kr_;
      koff[i] = (unsigned)(krow*CD + ((kc_ ^ ((i*4 + kr_) & 7))*8));
    }
  }
  const int      vrow0 = wv_*32 + (lane>>3);
  const unsigned vcs   = (unsigned)(((lane&7) ^ (lane>>3))*8);

  // Q B-fragments, iter- and teacher-invariant
  short8 qf[4][4];
#pragma unroll
  for (int qs=0;qs<4;qs++){
    const unsigned short* qr = Q + (size_t)(q0 + qs*16 + m)*CD + quad*8;
#pragma unroll
    for (int dk=0;dk<4;dk++) qf[qs][dk] = *(const short8*)(qr + dk*32);
  }

#define STAGE(buf, ktile) do { \
    const unsigned short* kt_src = K + (size_t)(ktile)*64*CD; \
    const unsigned short* vt_src = V + (size_t)(ktile)*64; \
    unsigned short* kl = (unsigned short*)smem + (buf)*16384 + wv_*2048; \
    unsigned short* vl = (unsigned short*)smem + (buf)*16384 + 8192 + wv_*2048; \
    _Pragma("unroll") \
    for (int i_=0;i_<4;i_++) \
      __builtin_amdgcn_global_load_lds( \
        (const __attribute__((address_space(1))) void*)(kt_src + koff[i_]), \
        (__attribute__((address_space(3))) void*)(kl + i_*512), 16, 0, 0); \
    _Pragma("unroll") \
    for (int i_=0;i_<4;i_++) \
      __builtin_amdgcn_global_load_lds( \
        (const __attribute__((address_space(1))) void*)(vt_src + (size_t)(vrow0 + i_*8)*HW + vcs), \
        (__attribute__((address_space(3))) void*)(vl + i_*512), 16, 0, 0); \
  } while(0)

  for (int t2=0; t2<2; t2++){
    const unsigned short* K = qkv + TS*(size_t)(1 + 2*t2) + (size_t)b*HW*CD;
    const unsigned short* V = qkv + TS*(size_t)(2 + 2*t2) + (size_t)b*CD*HW;

    floatx4 Oc[8][4];                  // k-partial O^T: [ct][qs] (AGPRs)
#pragma unroll
    for (int i=0;i<8;i++)
#pragma unroll
      for (int j=0;j<4;j++) Oc[i][j] = (floatx4)0.f;
    float lr[4] = {0.f,0.f,0.f,0.f};

    STAGE(0, 0);                       // prologue: tile 0 -> buf0

    for (int kt = 0; kt < NT; kt++){
      const int cur = kt & 1;
      __builtin_amdgcn_s_barrier();    // B1: all waves done computing buf[cur^1]
      if (kt < NT-1){
        STAGE(cur^1, kt+1);            // async DMA next tile
        asm volatile("s_waitcnt vmcnt(8)" ::: "memory");  // own buf[cur] DMAs done
      } else {
        asm volatile("s_waitcnt vmcnt(0)" ::: "memory");
      }
      __builtin_amdgcn_sched_barrier(0);
      __builtin_amdgcn_s_barrier();    // B2: everyone's buf[cur] complete
      asm volatile("" ::: "memory");

      const unsigned short* Kc = (const unsigned short*)smem + cur*16384;
      const unsigned short* Vc = (const unsigned short*)smem + cur*16384 + 8192;

      // QK: S^T[wv's 16k][64q]; A-frag = own-wave K rows, swizzled read
      short8 af[4];
#pragma unroll
      for (int dk=0;dk<4;dk++)
        af[dk] = *(const short8*)&Kc[(wv_*16 + m)*128 + (((dk*4 + quad) ^ (m & 7))*8)];

      short4v pfv[4];
#pragma unroll
      for (int qs=0;qs<4;qs++){
        floatx4 acc = (floatx4)0.f;
#pragma unroll
        for (int dk=0;dk<4;dk++)
          acc = __builtin_amdgcn_mfma_f32_16x16x32_bf16(af[dk], qf[qs][dk], acc, 0,0,0);
        union { float f; unsigned u; } c0, c1, c2, c3;
        c0.f = __builtin_amdgcn_exp2f(acc[0]);
        c1.f = __builtin_amdgcn_exp2f(acc[1]);
        c2.f = __builtin_amdgcn_exp2f(acc[2]);
        c3.f = __builtin_amdgcn_exp2f(acc[3]);
        lr[qs] += (c0.f + c1.f) + (c2.f + c3.f);
        union { unsigned u[2]; short4v s; } pk;
        pk.u[0] = (c1.u & 0xFFFF0000u) | (c0.u >> 16);
        pk.u[1] = (c3.u & 0xFFFF0000u) | (c2.u >> 16);
        pfv[qs] = pk.s;
      }

      // PV (K=16): O^T += V^T[c][wv's 16k] * P^T; swizzled b64 A-frag reads
#pragma unroll
      for (int ct=0;ct<8;ct++){
        short4v vf = *(const short4v*)&Vc[(ct*16 + m)*64 +
                       (((2*wv_ + (quad>>1)) ^ (m & 7))*8) + (quad&1)*4];
#pragma unroll
        for (int qs=0;qs<4;qs++)
          Oc[ct][qs] = MFMA16(vf, pfv[qs], Oc[ct][qs]);
      }
    }

    // ---- epilogue: cross-wave reduction of lr and O partials ----
#pragma unroll
    for (int qs=0;qs<4;qs++){
      lr[qs] += __shfl_xor(lr[qs], 16, 64);
      lr[qs] += __shfl_xor(lr[qs], 32, 64);
    }
    if (quad == 0){
#pragma unroll
      for (int qs=0;qs<4;qs++) lrb[wv_*64 + qs*16 + m] = lr[qs];
    }
    __syncthreads();
    if (tid < 64)
      invL[tid] = 1.f/(lrb[tid] + lrb[64+tid] + lrb[128+tid] + lrb[192+tid]);
    __syncthreads();

    float* Of = (float*)smem;          // overlaps K/V buffers (all reads done)
    unsigned short* ob = Og + ((size_t)t2*NB + b)*HW*CD + (size_t)q0*CD;
    const int qlr = wv_*16 + (lane>>2);
    const int c8  = (lane&3)*8;
#pragma unroll
    for (int rd=0; rd<4; rd++){
#pragma unroll
      for (int cc=0; cc<2; cc++){
#pragma unroll
        for (int qs=0; qs<4; qs++)
          *(floatx4*)&Of[wv_*2304 + (qs*16+m)*36 + cc*16 + quad*4] = Oc[rd*2+cc][qs];
      }
      __syncthreads();
      floatx4 s0 = (floatx4)0.f, s1 = (floatx4)0.f;
#pragma unroll
      for (int w=0; w<4; w++){
        s0 += *(const floatx4*)&Of[w*2304 + qlr*36 + c8];
        s1 += *(const floatx4*)&Of[w*2304 + qlr*36 + c8 + 4];
      }
      float iv = invL[qlr];
      short8 o;
#pragma unroll
      for (int j=0;j<4;j++){
        o[j]   = (short)f2b(s0[j]*iv);
        o[4+j] = (short)f2b(s1[j]*iv);
      }
      *(short8*)&ob[(size_t)qlr*CD + rd*32 + c8] = o;
      __syncthreads();
    }
  }
#undef STAGE
}

// ---------------------------------------------------------------------------
// out[b,c,hw] = s[b,c,hw] + 0.5*(O1[b,hw,c] + O2[b,hw,c])  (R4 revert)
// ---------------------------------------------------------------------------
__global__ __launch_bounds__(256) void combine_kernel(
    const float* __restrict__ s, const unsigned short* __restrict__ Og,
    float* __restrict__ out)
{
  __shared__ float T[32][129];
  const int b   = blockIdx.y;
  const int hw0 = blockIdx.x * 32;
  const int tid = threadIdx.x;
  const unsigned short* O1 = Og + ((size_t)b*HW + hw0)*CD;
  const unsigned short* O2 = O1 + (size_t)NB*HW*CD;
  for (int i=0;i<2;i++){
    int flat = (tid + i*256)*8;
    int row = flat >> 7, col = flat & 127;
    short8 a  = *(const short8*)(O1 + (size_t)row*CD + col);
    short8 c2 = *(const short8*)(O2 + (size_t)row*CD + col);
    for (int j=0;j<8;j++)
      T[row][col+j] = 0.5f*(b2f((unsigned short)a[j]) + b2f((unsigned short)c2[j]));
  }
  __syncthreads();
  const int c  = tid >> 1;
  const int h0 = (tid & 1)*16;
  const float* sr = s   + ((size_t)b*CD + c)*HW + hw0 + h0;
  float*     orow = out + ((size_t)b*CD + c)*HW + hw0 + h0;
  for (int j0=0;j0<16;j0+=4){
    floatx4 sv = *(const floatx4*)(sr + j0);
    floatx4 ov;
    for (int jj=0;jj<4;jj++) ov[jj] = sv[jj] + T[h0+j0+jj][c];
    *(floatx4*)(orow + j0) = ov;
  }
}

extern "C" void kernel_launch(void* const* d_in, const int* in_sizes, int n_in,
                              void* d_out, int out_size, void* d_ws, size_t ws_size,
                              hipStream_t stream)
{
  const float* s  = (const float*)d_in[0];
  const float* t1 = (const float*)d_in[1];
  const float* t2 = (const float*)d_in[2];
  const float* wq = (const float*)d_in[3];
  const float* bq = (const float*)d_in[4];
  const float* wk = (const float*)d_in[5];
  const float* bk = (const float*)d_in[6];
  const float* wv = (const float*)d_in[7];
  const float* bv = (const float*)d_in[8];
  float* out = (float*)d_out;

  unsigned short* qkv = (unsigned short*)d_ws;                 // 5*NB*HW*CD bf16
  unsigned short* Og  = qkv + (size_t)5*NB*HW*CD;              // 2*NB*HW*CD bf16
  unsigned short* Wb  = Og  + (size_t)2*NB*HW*CD;              // 3*CD*CD bf16

  hipLaunchKernelGGL(wconv_kernel,   dim3(3),      dim3(256), 0, stream, wq, wk, wv, Wb);
  hipLaunchKernelGGL(proj_kernel,    dim3(49,8,3), dim3(256), 0, stream,
                     s, t1, t2, bq, bk, bv, Wb, qkv);
  hipLaunchKernelGGL(attn_kernel,    dim3(392),    dim3(256), 0, stream, qkv, Og);
  hipLaunchKernelGGL(combine_kernel, dim3(98,8),   dim3(256), 0, stream, s, Og, out);
}

// Round 8
// 289.039 us; speedup vs baseline: 1.4310x; 1.0885x over previous
//
#include <hip/hip_runtime.h>

#define HW 3136
#define NB 8
#define CD 128
#define NT (HW/64)
// C^-0.5 * log2(e), folded into the Q projection so attn can use exp2 directly
#define QSCALE 0.12751750206f

typedef __attribute__((ext_vector_type(8))) short short8;
typedef __attribute__((ext_vector_type(4))) short short4v;
typedef __attribute__((ext_vector_type(4))) float floatx4;
typedef __attribute__((ext_vector_type(4))) unsigned short ushort4v;

static __device__ __forceinline__ unsigned short f2b(float f){
  union { float f; unsigned u; } v; v.f = f;
  unsigned r = v.u + 0x7FFFu + ((v.u >> 16) & 1u);
  return (unsigned short)(r >> 16);
}
static __device__ __forceinline__ float b2f(unsigned short h){
  union { unsigned u; float f; } v; v.u = ((unsigned)h) << 16;
  return v.f;
}

// K=16 bf16 MFMA: builtin spelling differs across ROCm versions; hedge.
#if __has_builtin(__builtin_amdgcn_mfma_f32_16x16x16bf16_1k)
#define MFMA16(a,b,c) __builtin_amdgcn_mfma_f32_16x16x16bf16_1k(a,b,c,0,0,0)
#elif __has_builtin(__builtin_amdgcn_mfma_f32_16x16x16_bf16)
#define MFMA16(a,b,c) __builtin_amdgcn_mfma_f32_16x16x16_bf16(a,b,c,0,0,0)
#else
static __device__ __forceinline__ floatx4 mfma16_asm(short4v a, short4v b, floatx4 c){
  floatx4 d;
  asm volatile("v_mfma_f32_16x16x16_bf16 %0, %1, %2, %3\n\ts_nop 7\n\ts_nop 7"
               : "=v"(d) : "v"(a), "v"(b), "v"(c));
  return d;
}
#define MFMA16(a,b,c) mfma16_asm(a,b,c)
#endif

// ---------------------------------------------------------------------------
// 1x1 conv projections via MFMA. R4 structure (5 jobs, WL LDS staging — the
// verified rest=129 config; R6 W-direct and R7 job-merge both regressed).
// NEW (R8): Q/K jobs swap MFMA operands — D = mfma(W,X) = [o][hw], so each
// lane holds 4 consecutive c at fixed hw -> epilogue is 8 x 8B vector stores
// instead of 32 scalar 2B stores (4x fewer store instructions, same trick as
// attn's swapped QK^T, already HW-verified). V jobs unchanged (already 8B).
// ---------------------------------------------------------------------------
__global__ __launch_bounds__(256) void proj_kernel(
    const float* __restrict__ s, const float* __restrict__ t1, const float* __restrict__ t2,
    const float* __restrict__ wq, const float* __restrict__ bq,
    const float* __restrict__ wk, const float* __restrict__ bk,
    const float* __restrict__ wv, const float* __restrict__ bv,
    unsigned short* __restrict__ qkv)
{
  __shared__ __align__(16) unsigned short WL[CD][136];   // W bf16 [o][c]
  __shared__ __align__(16) unsigned short xsT[64][136];  // X^T bf16 [hw_local][c]
  const int job = blockIdx.z;
  const float* x; const float* w; const float* bias; float scl; int cmajor; size_t dstoff;
  switch(job){
    case 0: x=s;  w=wq; bias=bq; scl=QSCALE; cmajor=0; dstoff=0; break;
    case 1: x=t1; w=wk; bias=bk; scl=1.f;    cmajor=0; dstoff=1; break;
    case 2: x=t1; w=wv; bias=bv; scl=1.f;    cmajor=1; dstoff=2; break;
    case 3: x=t2; w=wk; bias=bk; scl=1.f;    cmajor=0; dstoff=3; break;
    default:x=t2; w=wv; bias=bv; scl=1.f;    cmajor=1; dstoff=4; break;
  }
  const size_t TS = (size_t)NB*HW*CD;
  const int b   = blockIdx.y;
  const int hw0 = blockIdx.x * 64;
  const int tid = threadIdx.x;

  // stage W (f32 -> bf16, rounded)
  for (int i = 0; i < 16; i++){
    int flat = tid + i*256;                 // o*32 + cq/4
    int o = flat >> 5, cq = (flat & 31)*4;
    floatx4 wv4 = *(const floatx4*)(w + (size_t)o*CD + cq);
    ushort4v pk;
    for (int j=0;j<4;j++) pk[j] = f2b(wv4[j]);
    *(ushort4v*)&WL[o][cq] = pk;
  }
  // stage X^T (transpose during store)
  const float* xb = x + (size_t)b*CD*HW + hw0;
  for (int i = 0; i < 8; i++){
    int flat = (tid + i*256)*4;             // c*64 + hh
    int c = flat >> 6, hh = flat & 63;
    floatx4 xv = *(const floatx4*)(xb + (size_t)c*HW + hh);
    for (int j=0;j<4;j++) xsT[hh+j][c] = f2b(xv[j]);
  }
  __syncthreads();

  const int m = tid & 15, quad = (tid >> 4) & 3, wv_ = tid >> 6;
  short8 af[4];
#pragma unroll
  for (int dk=0;dk<4;dk++)
    af[dk] = *(const short8*)&xsT[wv_*16 + m][dk*32 + quad*8];

  unsigned short* dstK = qkv + dstoff*TS + ((size_t)b*HW + hw0)*CD;
  unsigned short* dstV = qkv + dstoff*TS + (size_t)b*CD*HW;
  if (!cmajor){
    // swapped operands: D[o][hw]; lane holds o = nt*16+quad*4+r, hw = wv*16+m
#pragma unroll
    for (int nt=0;nt<8;nt++){
      floatx4 acc = *(const floatx4*)(bias + nt*16 + quad*4);
#pragma unroll
      for (int dk=0;dk<4;dk++){
        short8 bf = *(const short8*)&WL[nt*16 + m][dk*32 + quad*8];
        acc = __builtin_amdgcn_mfma_f32_16x16x32_bf16(bf, af[dk], acc, 0,0,0);
      }
      ushort4v pk;
      for (int r=0;r<4;r++) pk[r] = f2b(acc[r]*scl);
      *(ushort4v*)&dstK[(size_t)(wv_*16 + m)*CD + nt*16 + quad*4] = pk;
    }
  } else {
    // original order: D[hw][c]; lane holds 4 hw at fixed c -> [c][hw] 8B stores
    float bb[8];
#pragma unroll
    for (int nt=0;nt<8;nt++) bb[nt] = bias[nt*16 + m];
#pragma unroll
    for (int nt=0;nt<8;nt++){
      floatx4 acc = {bb[nt],bb[nt],bb[nt],bb[nt]};
#pragma unroll
      for (int dk=0;dk<4;dk++){
        short8 bf = *(const short8*)&WL[nt*16 + m][dk*32 + quad*8];
        acc = __builtin_amdgcn_mfma_f32_16x16x32_bf16(af[dk], bf, acc, 0,0,0);
      }
      ushort4v pk;
      for (int r=0;r<4;r++) pk[r] = f2b(acc[r]*scl);
      *(ushort4v*)&dstV[(size_t)(nt*16 + m)*HW + hw0 + wv_*16 + quad*4] = pk;
    }
  }
}

// ---------------------------------------------------------------------------
// Flash attention — byte-exact R4/R7 (verified 158-159us).
// ---------------------------------------------------------------------------
__global__ __launch_bounds__(256,2) void attn_kernel(
    const unsigned short* __restrict__ qkv,
    unsigned short* __restrict__ Og)
{
  // shorts: K0 [0,8192) V0 [8192,16384) K1 [16384,24576) V1 [24576,32768)
  __shared__ __align__(16) unsigned short smem[32768 + 512 + 128]; // 66816 B
  float* lrb  = (float*)(smem + 32768);        // [4 wv][64 q]
  float* invL = (float*)(smem + 32768 + 512);  // [64 q]

  const int l  = blockIdx.x;       // 392 = 8 XCD-pinned b values x 49 qt
  const int b  = l & 7;
  const int qt = l >> 3;
  const size_t TS = (size_t)NB*HW*CD;
  const unsigned short* Q = qkv + (size_t)b*HW*CD;

  const int tid  = threadIdx.x;
  const int wv_  = tid >> 6;
  const int lane = tid & 63;
  const int m    = lane & 15;
  const int quad = lane >> 4;
  const int q0   = qt*64;

  // DMA source offsets (shorts), pre-swizzled so linear LDS dest + swizzled
  // ds_read agree: LDS(row, col16) holds logical col16 ^ (row&7).
  unsigned koff[4];
  {
    const int kr_ = lane >> 4, kc_ = lane & 15;
#pragma unroll
    for (int i=0;i<4;i++){
      const int krow = wv_*16 + i*4 + kr_;
      koff[i] = (unsigned)(krow*CD + ((kc_ ^ ((i*4 + kr_) & 7))*8));
    }
  }
  const int      vrow0 = wv_*32 + (lane>>3);
  const unsigned vcs   = (unsigned)(((lane&7) ^ (lane>>3))*8);

  // Q B-fragments, iter- and teacher-invariant
  short8 qf[4][4];
#pragma unroll
  for (int qs=0;qs<4;qs++){
    const unsigned short* qr = Q + (size_t)(q0 + qs*16 + m)*CD + quad*8;
#pragma unroll
    for (int dk=0;dk<4;dk++) qf[qs][dk] = *(const short8*)(qr + dk*32);
  }

#define STAGE(buf, ktile) do { \
    const unsigned short* kt_src = K + (size_t)(ktile)*64*CD; \
    const unsigned short* vt_src = V + (size_t)(ktile)*64; \
    unsigned short* kl = (unsigned short*)smem + (buf)*16384 + wv_*2048; \
    unsigned short* vl = (unsigned short*)smem + (buf)*16384 + 8192 + wv_*2048; \
    _Pragma("unroll") \
    for (int i_=0;i_<4;i_++) \
      __builtin_amdgcn_global_load_lds( \
        (const __attribute__((address_space(1))) void*)(kt_src + koff[i_]), \
        (__attribute__((address_space(3))) void*)(kl + i_*512), 16, 0, 0); \
    _Pragma("unroll") \
    for (int i_=0;i_<4;i_++) \
      __builtin_amdgcn_global_load_lds( \
        (const __attribute__((address_space(1))) void*)(vt_src + (size_t)(vrow0 + i_*8)*HW + vcs), \
        (__attribute__((address_space(3))) void*)(vl + i_*512), 16, 0, 0); \
  } while(0)

  for (int t2=0; t2<2; t2++){
    const unsigned short* K = qkv + TS*(size_t)(1 + 2*t2) + (size_t)b*HW*CD;
    const unsigned short* V = qkv + TS*(size_t)(2 + 2*t2) + (size_t)b*CD*HW;

    floatx4 Oc[8][4];                  // k-partial O^T: [ct][qs] (AGPRs)
#pragma unroll
    for (int i=0;i<8;i++)
#pragma unroll
      for (int j=0;j<4;j++) Oc[i][j] = (floatx4)0.f;
    float lr[4] = {0.f,0.f,0.f,0.f};

    STAGE(0, 0);                       // prologue: tile 0 -> buf0

    for (int kt = 0; kt < NT; kt++){
      const int cur = kt & 1;
      __builtin_amdgcn_s_barrier();    // B1: all waves done computing buf[cur^1]
      if (kt < NT-1){
        STAGE(cur^1, kt+1);            // async DMA next tile
        asm volatile("s_waitcnt vmcnt(8)" ::: "memory");  // own buf[cur] DMAs done
      } else {
        asm volatile("s_waitcnt vmcnt(0)" ::: "memory");
      }
      __builtin_amdgcn_sched_barrier(0);
      __builtin_amdgcn_s_barrier();    // B2: everyone's buf[cur] complete
      asm volatile("" ::: "memory");

      const unsigned short* Kc = (const unsigned short*)smem + cur*16384;
      const unsigned short* Vc = (const unsigned short*)smem + cur*16384 + 8192;

      // QK: S^T[wv's 16k][64q]; A-frag = own-wave K rows, swizzled read
      short8 af[4];
#pragma unroll
      for (int dk=0;dk<4;dk++)
        af[dk] = *(const short8*)&Kc[(wv_*16 + m)*128 + (((dk*4 + quad) ^ (m & 7))*8)];

      short4v pfv[4];
#pragma unroll
      for (int qs=0;qs<4;qs++){
        floatx4 acc = (floatx4)0.f;
#pragma unroll
        for (int dk=0;dk<4;dk++)
          acc = __builtin_amdgcn_mfma_f32_16x16x32_bf16(af[dk], qf[qs][dk], acc, 0,0,0);
        union { float f; unsigned u; } c0, c1, c2, c3;
        c0.f = __builtin_amdgcn_exp2f(acc[0]);
        c1.f = __builtin_amdgcn_exp2f(acc[1]);
        c2.f = __builtin_amdgcn_exp2f(acc[2]);
        c3.f = __builtin_amdgcn_exp2f(acc[3]);
        lr[qs] += (c0.f + c1.f) + (c2.f + c3.f);
        union { unsigned u[2]; short4v s; } pk;
        pk.u[0] = (c1.u & 0xFFFF0000u) | (c0.u >> 16);
        pk.u[1] = (c3.u & 0xFFFF0000u) | (c2.u >> 16);
        pfv[qs] = pk.s;
      }

      // PV (K=16): O^T += V^T[c][wv's 16k] * P^T; swizzled b64 A-frag reads
#pragma unroll
      for (int ct=0;ct<8;ct++){
        short4v vf = *(const short4v*)&Vc[(ct*16 + m)*64 +
                       (((2*wv_ + (quad>>1)) ^ (m & 7))*8) + (quad&1)*4];
#pragma unroll
        for (int qs=0;qs<4;qs++)
          Oc[ct][qs] = MFMA16(vf, pfv[qs], Oc[ct][qs]);
      }
    }

    // ---- epilogue: cross-wave reduction of lr and O partials ----
#pragma unroll
    for (int qs=0;qs<4;qs++){
      lr[qs] += __shfl_xor(lr[qs], 16, 64);
      lr[qs] += __shfl_xor(lr[qs], 32, 64);
    }
    if (quad == 0){
#pragma unroll
      for (int qs=0;qs<4;qs++) lrb[wv_*64 + qs*16 + m] = lr[qs];
    }
    __syncthreads();
    if (tid < 64)
      invL[tid] = 1.f/(lrb[tid] + lrb[64+tid] + lrb[128+tid] + lrb[192+tid]);
    __syncthreads();

    float* Of = (float*)smem;          // overlaps K/V buffers (all reads done)
    unsigned short* ob = Og + ((size_t)t2*NB + b)*HW*CD + (size_t)q0*CD;
    const int qlr = wv_*16 + (lane>>2);
    const int c8  = (lane&3)*8;
#pragma unroll
    for (int rd=0; rd<4; rd++){
#pragma unroll
      for (int cc=0; cc<2; cc++){
#pragma unroll
        for (int qs=0; qs<4; qs++)
          *(floatx4*)&Of[wv_*2304 + (qs*16+m)*36 + cc*16 + quad*4] = Oc[rd*2+cc][qs];
      }
      __syncthreads();
      floatx4 s0 = (floatx4)0.f, s1 = (floatx4)0.f;
#pragma unroll
      for (int w=0; w<4; w++){
        s0 += *(const floatx4*)&Of[w*2304 + qlr*36 + c8];
        s1 += *(const floatx4*)&Of[w*2304 + qlr*36 + c8 + 4];
      }
      float iv = invL[qlr];
      short8 o;
#pragma unroll
      for (int j=0;j<4;j++){
        o[j]   = (short)f2b(s0[j]*iv);
        o[4+j] = (short)f2b(s1[j]*iv);
      }
      *(short8*)&ob[(size_t)qlr*CD + rd*32 + c8] = o;
      __syncthreads();
    }
  }
#undef STAGE
}

// ---------------------------------------------------------------------------
// out[b,c,hw] = s[b,c,hw] + 0.5*(O1[b,hw,c] + O2[b,hw,c])
// R8: phase-1 vectorized (b128 LDS writes, pad 132 keeps 16B alignment).
// ---------------------------------------------------------------------------
__global__ __launch_bounds__(256) void combine_kernel(
    const float* __restrict__ s, const unsigned short* __restrict__ Og,
    float* __restrict__ out)
{
  __shared__ __align__(16) float T[32][132];
  const int b   = blockIdx.y;
  const int hw0 = blockIdx.x * 32;
  const int tid = threadIdx.x;
  const unsigned short* O1 = Og + ((size_t)b*HW + hw0)*CD;
  const unsigned short* O2 = O1 + (size_t)NB*HW*CD;
  for (int i=0;i<2;i++){
    int flat = tid + i*256;              // 0..511
    int row = flat >> 4, col0 = (flat & 15)*8;
    short8 a  = *(const short8*)(O1 + (size_t)row*CD + col0);
    short8 c2 = *(const short8*)(O2 + (size_t)row*CD + col0);
    floatx4 v0, v1;
#pragma unroll
    for (int j=0;j<4;j++){
      v0[j] = 0.5f*(b2f((unsigned short)a[j])   + b2f((unsigned short)c2[j]));
      v1[j] = 0.5f*(b2f((unsigned short)a[4+j]) + b2f((unsigned short)c2[4+j]));
    }
    *(floatx4*)&T[row][col0]   = v0;
    *(floatx4*)&T[row][col0+4] = v1;
  }
  __syncthreads();
  const int c  = tid >> 1;
  const int h0 = (tid & 1)*16;
  const float* sr = s   + ((size_t)b*CD + c)*HW + hw0 + h0;
  float*     orow = out + ((size_t)b*CD + c)*HW + hw0 + h0;
  for (int j0=0;j0<16;j0+=4){
    floatx4 sv = *(const floatx4*)(sr + j0);
    floatx4 ov;
    for (int jj=0;jj<4;jj++) ov[jj] = sv[jj] + T[h0+j0+jj][c];
    *(floatx4*)(orow + j0) = ov;
  }
}

extern "C" void kernel_launch(void* const* d_in, const int* in_sizes, int n_in,
                              void* d_out, int out_size, void* d_ws, size_t ws_size,
                              hipStream_t stream)
{
  const float* s  = (const float*)d_in[0];
  const float* t1 = (const float*)d_in[1];
  const float* t2 = (const float*)d_in[2];
  const float* wq = (const float*)d_in[3];
  const float* bq = (const float*)d_in[4];
  const float* wk = (const float*)d_in[5];
  const float* bk = (const float*)d_in[6];
  const float* wv = (const float*)d_in[7];
  const float* bv = (const float*)d_in[8];
  float* out = (float*)d_out;

  unsigned short* qkv = (unsigned short*)d_ws;                 // 5*NB*HW*CD bf16
  unsigned short* Og  = qkv + (size_t)5*NB*HW*CD;              // 2*NB*HW*CD bf16

  hipLaunchKernelGGL(proj_kernel,    dim3(49,8,5), dim3(256), 0, stream,
                     s,t1,t2,wq,bq,wk,bk,wv,bv,qkv);
  hipLaunchKernelGGL(attn_kernel,    dim3(392),    dim3(256), 0, stream, qkv, Og);
  hipLaunchKernelGGL(combine_kernel, dim3(98,8),   dim3(256), 0, stream, s, Og, out);
}

// Round 9
// 274.189 us; speedup vs baseline: 1.5085x; 1.0542x over previous
//
#include <hip/hip_runtime.h>

#define HW 3136
#define NB 8
#define CD 128
#define NT (HW/64)
// C^-0.5 * log2(e), folded into the Q projection so attn can use exp2 directly
#define QSCALE 0.12751750206f

typedef __attribute__((ext_vector_type(8))) short short8;
typedef __attribute__((ext_vector_type(4))) short short4v;
typedef __attribute__((ext_vector_type(4))) float floatx4;
typedef __attribute__((ext_vector_type(4))) unsigned short ushort4v;

static __device__ __forceinline__ unsigned short f2b(float f){
  union { float f; unsigned u; } v; v.f = f;
  unsigned r = v.u + 0x7FFFu + ((v.u >> 16) & 1u);
  return (unsigned short)(r >> 16);
}
static __device__ __forceinline__ float b2f(unsigned short h){
  union { unsigned u; float f; } v; v.u = ((unsigned)h) << 16;
  return v.f;
}
// packed f32x2 -> bf16x2 (RNE), 1 instr vs 3 bitops; no builtin on gfx950
static __device__ __forceinline__ unsigned cvtpk(float lo, float hi){
  unsigned r;
  asm("v_cvt_pk_bf16_f32 %0, %1, %2" : "=v"(r) : "v"(lo), "v"(hi));
  return r;
}

// K=16 bf16 MFMA: builtin spelling differs across ROCm versions; hedge.
#if __has_builtin(__builtin_amdgcn_mfma_f32_16x16x16bf16_1k)
#define MFMA16(a,b,c) __builtin_amdgcn_mfma_f32_16x16x16bf16_1k(a,b,c,0,0,0)
#elif __has_builtin(__builtin_amdgcn_mfma_f32_16x16x16_bf16)
#define MFMA16(a,b,c) __builtin_amdgcn_mfma_f32_16x16x16_bf16(a,b,c,0,0,0)
#else
static __device__ __forceinline__ floatx4 mfma16_asm(short4v a, short4v b, floatx4 c){
  floatx4 d;
  asm volatile("v_mfma_f32_16x16x16_bf16 %0, %1, %2, %3\n\ts_nop 7\n\ts_nop 7"
               : "=v"(d) : "v"(a), "v"(b), "v"(c));
  return d;
}
#define MFMA16(a,b,c) mfma16_asm(a,b,c)
#endif

// ---------------------------------------------------------------------------
// 1x1 conv projections via MFMA (R8 version — rest invariant 126-132us across
// all proj variants; frozen as control).
// ---------------------------------------------------------------------------
__global__ __launch_bounds__(256) void proj_kernel(
    const float* __restrict__ s, const float* __restrict__ t1, const float* __restrict__ t2,
    const float* __restrict__ wq, const float* __restrict__ bq,
    const float* __restrict__ wk, const float* __restrict__ bk,
    const float* __restrict__ wv, const float* __restrict__ bv,
    unsigned short* __restrict__ qkv)
{
  __shared__ __align__(16) unsigned short WL[CD][136];   // W bf16 [o][c]
  __shared__ __align__(16) unsigned short xsT[64][136];  // X^T bf16 [hw_local][c]
  const int job = blockIdx.z;
  const float* x; const float* w; const float* bias; float scl; int cmajor; size_t dstoff;
  switch(job){
    case 0: x=s;  w=wq; bias=bq; scl=QSCALE; cmajor=0; dstoff=0; break;
    case 1: x=t1; w=wk; bias=bk; scl=1.f;    cmajor=0; dstoff=1; break;
    case 2: x=t1; w=wv; bias=bv; scl=1.f;    cmajor=1; dstoff=2; break;
    case 3: x=t2; w=wk; bias=bk; scl=1.f;    cmajor=0; dstoff=3; break;
    default:x=t2; w=wv; bias=bv; scl=1.f;    cmajor=1; dstoff=4; break;
  }
  const size_t TS = (size_t)NB*HW*CD;
  const int b   = blockIdx.y;
  const int hw0 = blockIdx.x * 64;
  const int tid = threadIdx.x;

  // stage W (f32 -> bf16, rounded)
  for (int i = 0; i < 16; i++){
    int flat = tid + i*256;                 // o*32 + cq/4
    int o = flat >> 5, cq = (flat & 31)*4;
    floatx4 wv4 = *(const floatx4*)(w + (size_t)o*CD + cq);
    ushort4v pk;
    for (int j=0;j<4;j++) pk[j] = f2b(wv4[j]);
    *(ushort4v*)&WL[o][cq] = pk;
  }
  // stage X^T (transpose during store)
  const float* xb = x + (size_t)b*CD*HW + hw0;
  for (int i = 0; i < 8; i++){
    int flat = (tid + i*256)*4;             // c*64 + hh
    int c = flat >> 6, hh = flat & 63;
    floatx4 xv = *(const floatx4*)(xb + (size_t)c*HW + hh);
    for (int j=0;j<4;j++) xsT[hh+j][c] = f2b(xv[j]);
  }
  __syncthreads();

  const int m = tid & 15, quad = (tid >> 4) & 3, wv_ = tid >> 6;
  short8 af[4];
#pragma unroll
  for (int dk=0;dk<4;dk++)
    af[dk] = *(const short8*)&xsT[wv_*16 + m][dk*32 + quad*8];

  unsigned short* dstK = qkv + dstoff*TS + ((size_t)b*HW + hw0)*CD;
  unsigned short* dstV = qkv + dstoff*TS + (size_t)b*CD*HW;
  if (!cmajor){
    // swapped operands: D[o][hw]; lane holds o = nt*16+quad*4+r, hw = wv*16+m
#pragma unroll
    for (int nt=0;nt<8;nt++){
      floatx4 acc = *(const floatx4*)(bias + nt*16 + quad*4);
#pragma unroll
      for (int dk=0;dk<4;dk++){
        short8 bf = *(const short8*)&WL[nt*16 + m][dk*32 + quad*8];
        acc = __builtin_amdgcn_mfma_f32_16x16x32_bf16(bf, af[dk], acc, 0,0,0);
      }
      ushort4v pk;
      for (int r=0;r<4;r++) pk[r] = f2b(acc[r]*scl);
      *(ushort4v*)&dstK[(size_t)(wv_*16 + m)*CD + nt*16 + quad*4] = pk;
    }
  } else {
    // original order: D[hw][c]; lane holds 4 hw at fixed c -> [c][hw] 8B stores
    float bb[8];
#pragma unroll
    for (int nt=0;nt<8;nt++) bb[nt] = bias[nt*16 + m];
#pragma unroll
    for (int nt=0;nt<8;nt++){
      floatx4 acc = {bb[nt],bb[nt],bb[nt],bb[nt]};
#pragma unroll
      for (int dk=0;dk<4;dk++){
        short8 bf = *(const short8*)&WL[nt*16 + m][dk*32 + quad*8];
        acc = __builtin_amdgcn_mfma_f32_16x16x32_bf16(af[dk], bf, acc, 0,0,0);
      }
      ushort4v pk;
      for (int r=0;r<4;r++) pk[r] = f2b(acc[r]*scl);
      *(ushort4v*)&dstV[(size_t)(nt*16 + m)*HW + hw0 + wv_*16 + quad*4] = pk;
    }
  }
}

// ---------------------------------------------------------------------------
// Flash attention — R4 structure (verified 158us) + two catalog techniques:
//  T5: s_setprio(1/0) around MFMA clusters. R8 cycle accounting shows the two
//      co-resident blocks run SERIALIZED (per-CU kt-pair cycles = sum of both
//      blocks' MFMA+VALU+LDS demand); setprio gives the CU scheduler the role
//      split it needs to overlap block A's MFMA with block B's exp2 (m191:
//      attn +4-7%; prereq = wave role diversity, satisfied by 2 drifting blocks).
//  T12: v_cvt_pk_bf16_f32 replaces 3-bitop truncate-pack (~32 VALU cyc/kt of
//      ~230; also upgrades P to RNE rounding).
// ---------------------------------------------------------------------------
__global__ __launch_bounds__(256,2) void attn_kernel(
    const unsigned short* __restrict__ qkv,
    unsigned short* __restrict__ Og)
{
  // shorts: K0 [0,8192) V0 [8192,16384) K1 [16384,24576) V1 [24576,32768)
  __shared__ __align__(16) unsigned short smem[32768 + 512 + 128]; // 66816 B
  float* lrb  = (float*)(smem + 32768);        // [4 wv][64 q]
  float* invL = (float*)(smem + 32768 + 512);  // [64 q]

  const int l  = blockIdx.x;       // 392 = 8 XCD-pinned b values x 49 qt
  const int b  = l & 7;
  const int qt = l >> 3;
  const size_t TS = (size_t)NB*HW*CD;
  const unsigned short* Q = qkv + (size_t)b*HW*CD;

  const int tid  = threadIdx.x;
  const int wv_  = tid >> 6;
  const int lane = tid & 63;
  const int m    = lane & 15;
  const int quad = lane >> 4;
  const int q0   = qt*64;

  // DMA source offsets (shorts), pre-swizzled so linear LDS dest + swizzled
  // ds_read agree: LDS(row, col16) holds logical col16 ^ (row&7).
  unsigned koff[4];
  {
    const int kr_ = lane >> 4, kc_ = lane & 15;
#pragma unroll
    for (int i=0;i<4;i++){
      const int krow = wv_*16 + i*4 + kr_;
      koff[i] = (unsigned)(krow*CD + ((kc_ ^ ((i*4 + kr_) & 7))*8));
    }
  }
  const int      vrow0 = wv_*32 + (lane>>3);
  const unsigned vcs   = (unsigned)(((lane&7) ^ (lane>>3))*8);

  // Q B-fragments, iter- and teacher-invariant
  short8 qf[4][4];
#pragma unroll
  for (int qs=0;qs<4;qs++){
    const unsigned short* qr = Q + (size_t)(q0 + qs*16 + m)*CD + quad*8;
#pragma unroll
    for (int dk=0;dk<4;dk++) qf[qs][dk] = *(const short8*)(qr + dk*32);
  }

#define STAGE(buf, ktile) do { \
    const unsigned short* kt_src = K + (size_t)(ktile)*64*CD; \
    const unsigned short* vt_src = V + (size_t)(ktile)*64; \
    unsigned short* kl = (unsigned short*)smem + (buf)*16384 + wv_*2048; \
    unsigned short* vl = (unsigned short*)smem + (buf)*16384 + 8192 + wv_*2048; \
    _Pragma("unroll") \
    for (int i_=0;i_<4;i_++) \
      __builtin_amdgcn_global_load_lds( \
        (const __attribute__((address_space(1))) void*)(kt_src + koff[i_]), \
        (__attribute__((address_space(3))) void*)(kl + i_*512), 16, 0, 0); \
    _Pragma("unroll") \
    for (int i_=0;i_<4;i_++) \
      __builtin_amdgcn_global_load_lds( \
        (const __attribute__((address_space(1))) void*)(vt_src + (size_t)(vrow0 + i_*8)*HW + vcs), \
        (__attribute__((address_space(3))) void*)(vl + i_*512), 16, 0, 0); \
  } while(0)

  for (int t2=0; t2<2; t2++){
    const unsigned short* K = qkv + TS*(size_t)(1 + 2*t2) + (size_t)b*HW*CD;
    const unsigned short* V = qkv + TS*(size_t)(2 + 2*t2) + (size_t)b*CD*HW;

    floatx4 Oc[8][4];                  // k-partial O^T: [ct][qs] (AGPRs)
#pragma unroll
    for (int i=0;i<8;i++)
#pragma unroll
      for (int j=0;j<4;j++) Oc[i][j] = (floatx4)0.f;
    float lr[4] = {0.f,0.f,0.f,0.f};

    STAGE(0, 0);                       // prologue: tile 0 -> buf0

    for (int kt = 0; kt < NT; kt++){
      const int cur = kt & 1;
      __builtin_amdgcn_s_barrier();    // B1: all waves done computing buf[cur^1]
      if (kt < NT-1){
        STAGE(cur^1, kt+1);            // async DMA next tile
        asm volatile("s_waitcnt vmcnt(8)" ::: "memory");  // own buf[cur] DMAs done
      } else {
        asm volatile("s_waitcnt vmcnt(0)" ::: "memory");
      }
      __builtin_amdgcn_sched_barrier(0);
      __builtin_amdgcn_s_barrier();    // B2: everyone's buf[cur] complete
      asm volatile("" ::: "memory");

      const unsigned short* Kc = (const unsigned short*)smem + cur*16384;
      const unsigned short* Vc = (const unsigned short*)smem + cur*16384 + 8192;

      // QK: S^T[wv's 16k][64q]; A-frag = own-wave K rows, swizzled read
      short8 af[4];
#pragma unroll
      for (int dk=0;dk<4;dk++)
        af[dk] = *(const short8*)&Kc[(wv_*16 + m)*128 + (((dk*4 + quad) ^ (m & 7))*8)];

      short4v pfv[4];
#pragma unroll
      for (int qs=0;qs<4;qs++){
        floatx4 acc = (floatx4)0.f;
        __builtin_amdgcn_s_setprio(1);           // T5: MFMA cluster priority
#pragma unroll
        for (int dk=0;dk<4;dk++)
          acc = __builtin_amdgcn_mfma_f32_16x16x32_bf16(af[dk], qf[qs][dk], acc, 0,0,0);
        __builtin_amdgcn_s_setprio(0);           // exp2 phase at low prio
        float c0 = __builtin_amdgcn_exp2f(acc[0]);
        float c1 = __builtin_amdgcn_exp2f(acc[1]);
        float c2 = __builtin_amdgcn_exp2f(acc[2]);
        float c3 = __builtin_amdgcn_exp2f(acc[3]);
        lr[qs] += (c0 + c1) + (c2 + c3);
        union { unsigned u[2]; short4v s; } pk;
        pk.u[0] = cvtpk(c0, c1);                 // T12: packed RNE convert
        pk.u[1] = cvtpk(c2, c3);
        pfv[qs] = pk.s;
      }

      // PV (K=16): O^T += V^T[c][wv's 16k] * P^T; swizzled b64 A-frag reads
      __builtin_amdgcn_s_setprio(1);             // T5: PV MFMA cluster
#pragma unroll
      for (int ct=0;ct<8;ct++){
        short4v vf = *(const short4v*)&Vc[(ct*16 + m)*64 +
                       (((2*wv_ + (quad>>1)) ^ (m & 7))*8) + (quad&1)*4];
#pragma unroll
        for (int qs=0;qs<4;qs++)
          Oc[ct][qs] = MFMA16(vf, pfv[qs], Oc[ct][qs]);
      }
      __builtin_amdgcn_s_setprio(0);
    }

    // ---- epilogue: cross-wave reduction of lr and O partials ----
#pragma unroll
    for (int qs=0;qs<4;qs++){
      lr[qs] += __shfl_xor(lr[qs], 16, 64);
      lr[qs] += __shfl_xor(lr[qs], 32, 64);
    }
    if (quad == 0){
#pragma unroll
      for (int qs=0;qs<4;qs++) lrb[wv_*64 + qs*16 + m] = lr[qs];
    }
    __syncthreads();
    if (tid < 64)
      invL[tid] = 1.f/(lrb[tid] + lrb[64+tid] + lrb[128+tid] + lrb[192+tid]);
    __syncthreads();

    float* Of = (float*)smem;          // overlaps K/V buffers (all reads done)
    unsigned short* ob = Og + ((size_t)t2*NB + b)*HW*CD + (size_t)q0*CD;
    const int qlr = wv_*16 + (lane>>2);
    const int c8  = (lane&3)*8;
#pragma unroll
    for (int rd=0; rd<4; rd++){
#pragma unroll
      for (int cc=0; cc<2; cc++){
#pragma unroll
        for (int qs=0; qs<4; qs++)
          *(floatx4*)&Of[wv_*2304 + (qs*16+m)*36 + cc*16 + quad*4] = Oc[rd*2+cc][qs];
      }
      __syncthreads();
      floatx4 s0 = (floatx4)0.f, s1 = (floatx4)0.f;
#pragma unroll
      for (int w=0; w<4; w++){
        s0 += *(const floatx4*)&Of[w*2304 + qlr*36 + c8];
        s1 += *(const floatx4*)&Of[w*2304 + qlr*36 + c8 + 4];
      }
      float iv = invL[qlr];
      short8 o;
#pragma unroll
      for (int j=0;j<4;j++){
        o[j]   = (short)f2b(s0[j]*iv);
        o[4+j] = (short)f2b(s1[j]*iv);
      }
      *(short8*)&ob[(size_t)qlr*CD + rd*32 + c8] = o;
      __syncthreads();
    }
  }
#undef STAGE
}

// ---------------------------------------------------------------------------
// out[b,c,hw] = s[b,c,hw] + 0.5*(O1[b,hw,c] + O2[b,hw,c])  (R8 version)
// ---------------------------------------------------------------------------
__global__ __launch_bounds__(256) void combine_kernel(
    const float* __restrict__ s, const unsigned short* __restrict__ Og,
    float* __restrict__ out)
{
  __shared__ __align__(16) float T[32][132];
  const int b   = blockIdx.y;
  const int hw0 = blockIdx.x * 32;
  const int tid = threadIdx.x;
  const unsigned short* O1 = Og + ((size_t)b*HW + hw0)*CD;
  const unsigned short* O2 = O1 + (size_t)NB*HW*CD;
  for (int i=0;i<2;i++){
    int flat = tid + i*256;              // 0..511
    int row = flat >> 4, col0 = (flat & 15)*8;
    short8 a  = *(const short8*)(O1 + (size_t)row*CD + col0);
    short8 c2 = *(const short8*)(O2 + (size_t)row*CD + col0);
    floatx4 v0, v1;
#pragma unroll
    for (int j=0;j<4;j++){
      v0[j] = 0.5f*(b2f((unsigned short)a[j])   + b2f((unsigned short)c2[j]));
      v1[j] = 0.5f*(b2f((unsigned short)a[4+j]) + b2f((unsigned short)c2[4+j]));
    }
    *(floatx4*)&T[row][col0]   = v0;
    *(floatx4*)&T[row][col0+4] = v1;
  }
  __syncthreads();
  const int c  = tid >> 1;
  const int h0 = (tid & 1)*16;
  const float* sr = s   + ((size_t)b*CD + c)*HW + hw0 + h0;
  float*     orow = out + ((size_t)b*CD + c)*HW + hw0 + h0;
  for (int j0=0;j0<16;j0+=4){
    floatx4 sv = *(const floatx4*)(sr + j0);
    floatx4 ov;
    for (int jj=0;jj<4;jj++) ov[jj] = sv[jj] + T[h0+j0+jj][c];
    *(floatx4*)(orow + j0) = ov;
  }
}

extern "C" void kernel_launch(void* const* d_in, const int* in_sizes, int n_in,
                              void* d_out, int out_size, void* d_ws, size_t ws_size,
                              hipStream_t stream)
{
  const float* s  = (const float*)d_in[0];
  const float* t1 = (const float*)d_in[1];
  const float* t2 = (const float*)d_in[2];
  const float* wq = (const float*)d_in[3];
  const float* bq = (const float*)d_in[4];
  const float* wk = (const float*)d_in[5];
  const float* bk = (const float*)d_in[6];
  const float* wv = (const float*)d_in[7];
  const float* bv = (const float*)d_in[8];
  float* out = (float*)d_out;

  unsigned short* qkv = (unsigned short*)d_ws;                 // 5*NB*HW*CD bf16
  unsigned short* Og  = qkv + (size_t)5*NB*HW*CD;              // 2*NB*HW*CD bf16

  hipLaunchKernelGGL(proj_kernel,    dim3(49,8,5), dim3(256), 0, stream,
                     s,t1,t2,wq,bq,wk,bk,wv,bv,qkv);
  hipLaunchKernelGGL(attn_kernel,    dim3(392),    dim3(256), 0, stream, qkv, Og);
  hipLaunchKernelGGL(combine_kernel, dim3(98,8),   dim3(256), 0, stream, s, Og, out);
}